// Round 2
// baseline (63.608 us; speedup 1.0000x reference)
//
#include <hip/hip_runtime.h>
#include <math.h>

#define NCAMS 6
#define CCH   32
#define YY    8
#define XX    256
#define ZZ    256
#define NVOX  (YY*XX*ZZ)        // 524288
#define IMG_H 224
#define IMG_W 400
#define FXV   56
#define FZV   100

#define FEATS_T_ELEMS (NCAMS*CCH*FXV*FZV)          // 1,075,200
#define VD_T_ELEMS    (NCAMS*IMG_H*IMG_W*2)        // 1,075,200
#define WS_NEED_BYTES ((size_t)(FEATS_T_ELEMS + VD_T_ELEMS) * 4)

// ---------------- prep: img_feats [6,32,56,100] -> [6,56,100,32] ----------------
__global__ __launch_bounds__(256) void prep_feats_t(
    const float* __restrict__ src, float* __restrict__ dst)
{
    int t = blockIdx.x * blockDim.x + threadIdx.x;   // over 6*56*100 = 33600
    if (t >= NCAMS * FXV * FZV) return;
    int b = t / (FXV * FZV);
    int r = t - b * (FXV * FZV);                     // xi*100 + yi
    float vals[CCH];
    #pragma unroll
    for (int c = 0; c < CCH; c++)
        vals[c] = src[(size_t)(b * CCH + c) * (FXV * FZV) + r];
    float4* d4 = (float4*)(dst + (size_t)t * CCH);
    #pragma unroll
    for (int j = 0; j < CCH / 4; j++)
        d4[j] = make_float4(vals[4*j], vals[4*j+1], vals[4*j+2], vals[4*j+3]);
}

// ---------------- prep: interleave variances+render_depth -> [6,224,400,2] -------
__global__ __launch_bounds__(256) void prep_vd_t(
    const float* __restrict__ var, const float* __restrict__ dep,
    float* __restrict__ dst)
{
    int t = blockIdx.x * blockDim.x + threadIdx.x;   // over 6*224*400 = 537600
    if (t >= NCAMS * IMG_H * IMG_W) return;
    float2 v = make_float2(var[t], dep[t]);
    ((float2*)dst)[t] = v;
}

// ---------------- main: channels-last fast path ----------------------------------
__global__ __launch_bounds__(256) void mvmap_fast(
    const float* __restrict__ feats_t,   // [6,56,100,32]
    const float* __restrict__ vd_t,      // [6,224,400,2]
    const float* __restrict__ coords,    // [1,524288,3]  (px, pz, h)
    const float* __restrict__ Ps,        // [6,4,4] cam2world
    const float* __restrict__ Ks,        // [6,3,3]
    float* __restrict__ out)
{
    __shared__ float sW2C[NCAMS][12];
    __shared__ float sK[NCAMS][9];

    if (threadIdx.x < NCAMS) {
        int b = threadIdx.x;
        const float* P = Ps + b * 16;
        float r00=P[0], r01=P[1], r02=P[2],  tx=P[3];
        float r10=P[4], r11=P[5], r12=P[6],  ty=P[7];
        float r20=P[8], r21=P[9], r22=P[10], tz=P[11];
        float det = r00*(r11*r22 - r12*r21)
                  - r01*(r10*r22 - r12*r20)
                  + r02*(r10*r21 - r11*r20);
        float id = 1.0f / det;
        float i00 =  (r11*r22 - r12*r21) * id;
        float i01 = -(r01*r22 - r02*r21) * id;
        float i02 =  (r01*r12 - r02*r11) * id;
        float i10 = -(r10*r22 - r12*r20) * id;
        float i11 =  (r00*r22 - r02*r20) * id;
        float i12 = -(r00*r12 - r02*r10) * id;
        float i20 =  (r10*r21 - r11*r20) * id;
        float i21 = -(r00*r21 - r01*r20) * id;
        float i22 =  (r00*r11 - r01*r10) * id;
        sW2C[b][0]=i00; sW2C[b][1]=i01; sW2C[b][2] =i02; sW2C[b][3] =-(i00*tx + i01*ty + i02*tz);
        sW2C[b][4]=i10; sW2C[b][5]=i11; sW2C[b][6] =i12; sW2C[b][7] =-(i10*tx + i11*ty + i12*tz);
        sW2C[b][8]=i20; sW2C[b][9]=i21; sW2C[b][10]=i22; sW2C[b][11]=-(i20*tx + i21*ty + i22*tz);
        #pragma unroll
        for (int j = 0; j < 9; j++) sK[b][j] = Ks[b*9 + j];
    }
    __syncthreads();

    int n = blockIdx.x * blockDim.x + threadIdx.x;
    if (n >= NVOX) return;

    float px = coords[3*n + 0];
    float pz = coords[3*n + 1];
    float ph = coords[3*n + 2];

    float4 facc[CCH/4];
    #pragma unroll
    for (int j = 0; j < CCH/4; j++) facc[j] = make_float4(0.f, 0.f, 0.f, 0.f);
    float wsum = 0.0f, vsum = 0.0f, ndsum = 0.0f, zsum = 0.0f;

    for (int b = 0; b < NCAMS; b++) {
        float cx = sW2C[b][0]*px + sW2C[b][1]*pz + sW2C[b][2] *ph + sW2C[b][3];
        float cy = sW2C[b][4]*px + sW2C[b][5]*pz + sW2C[b][6] *ph + sW2C[b][7];
        float cz = sW2C[b][8]*px + sW2C[b][9]*pz + sW2C[b][10]*ph + sW2C[b][11];
        float u0 = sK[b][0]*cx + sK[b][1]*cy + sK[b][2]*cz;
        float v0 = sK[b][3]*cx + sK[b][4]*cy + sK[b][5]*cz;
        float zc = sK[b][6]*cx + sK[b][7]*cy + sK[b][8]*cz;
        float zsafe = (fabsf(zc) < 1e-6f) ? 1e-6f : zc;
        float u = u0 / zsafe;
        float v = v0 / zsafe;
        bool mask = (zc > 1e-3f) && (u >= 0.0f) && (u < (float)IMG_W)
                                 && (v >= 0.0f) && (v < (float)IMG_H);
        if (!mask) continue;

        wsum += 1.0f;
        zsum += zc;

        // ---- features: channels-last, 4 taps x 8 float4 loads ----
        {
            float xf = v * 0.25f - 0.5f;      // width dim (56)
            float yf = u * 0.25f - 0.5f;      // height dim (100)
            float x0f = floorf(xf), y0f = floorf(yf);
            float wx = xf - x0f, wy = yf - y0f;
            int x0 = (int)x0f, y0 = (int)y0f;
            float vx0 = (x0   >= 0 && x0   < FXV) ? 1.0f : 0.0f;
            float vx1 = (x0+1 >= 0 && x0+1 < FXV) ? 1.0f : 0.0f;
            float vy0 = (y0   >= 0 && y0   < FZV) ? 1.0f : 0.0f;
            float vy1 = (y0+1 >= 0 && y0+1 < FZV) ? 1.0f : 0.0f;
            float w00 = (1.0f-wx)*(1.0f-wy)*vx0*vy0;
            float w10 = wx*(1.0f-wy)*vx1*vy0;
            float w01 = (1.0f-wx)*wy*vx0*vy1;
            float w11 = wx*wy*vx1*vy1;
            int xi0 = min(max(x0,   0), FXV-1), xi1 = min(max(x0+1, 0), FXV-1);
            int yi0 = min(max(y0,   0), FZV-1), yi1 = min(max(y0+1, 0), FZV-1);
            const float* base = feats_t + (size_t)b * (FXV*FZV*CCH);
            const float4* p00 = (const float4*)(base + (xi0*FZV + yi0)*CCH);
            const float4* p01 = (const float4*)(base + (xi0*FZV + yi1)*CCH);
            const float4* p10 = (const float4*)(base + (xi1*FZV + yi0)*CCH);
            const float4* p11 = (const float4*)(base + (xi1*FZV + yi1)*CCH);
            #pragma unroll
            for (int j = 0; j < CCH/4; j++) {
                float4 a = p00[j], b2 = p01[j], c2 = p10[j], d2 = p11[j];
                facc[j].x += w00*a.x + w01*b2.x + w10*c2.x + w11*d2.x;
                facc[j].y += w00*a.y + w01*b2.y + w10*c2.y + w11*d2.y;
                facc[j].z += w00*a.z + w01*b2.z + w10*c2.z + w11*d2.z;
                facc[j].w += w00*a.w + w01*b2.w + w10*c2.w + w11*d2.w;
            }
        }

        // ---- variance+depth interleaved: 4 float2 loads ----
        {
            float xf = v - 0.5f;
            float yf = u - 0.5f;
            float x0f = floorf(xf), y0f = floorf(yf);
            float wx = xf - x0f, wy = yf - y0f;
            int x0 = (int)x0f, y0 = (int)y0f;
            float vx0 = (x0   >= 0 && x0   < IMG_H) ? 1.0f : 0.0f;
            float vx1 = (x0+1 >= 0 && x0+1 < IMG_H) ? 1.0f : 0.0f;
            float vy0 = (y0   >= 0 && y0   < IMG_W) ? 1.0f : 0.0f;
            float vy1 = (y0+1 >= 0 && y0+1 < IMG_W) ? 1.0f : 0.0f;
            float w00 = (1.0f-wx)*(1.0f-wy)*vx0*vy0;
            float w10 = wx*(1.0f-wy)*vx1*vy0;
            float w01 = (1.0f-wx)*wy*vx0*vy1;
            float w11 = wx*wy*vx1*vy1;
            int xi0 = min(max(x0,   0), IMG_H-1), xi1 = min(max(x0+1, 0), IMG_H-1);
            int yi0 = min(max(y0,   0), IMG_W-1), yi1 = min(max(y0+1, 0), IMG_W-1);
            const float2* pv = (const float2*)(vd_t) + (size_t)b * (IMG_H*IMG_W);
            float2 t00 = pv[xi0*IMG_W + yi0], t01 = pv[xi0*IMG_W + yi1];
            float2 t10 = pv[xi1*IMG_W + yi0], t11 = pv[xi1*IMG_W + yi1];
            vsum  += w00*t00.x + w01*t01.x + w10*t10.x + w11*t11.x;
            ndsum += w00*t00.y + w01*t01.y + w10*t10.y + w11*t11.y;
        }
    }

    float invd = 1.0f / (wsum + 1e-6f);
    #pragma unroll
    for (int j = 0; j < CCH/4; j++) {
        __builtin_nontemporal_store(facc[j].x * invd, &out[(size_t)(4*j+0) * NVOX + n]);
        __builtin_nontemporal_store(facc[j].y * invd, &out[(size_t)(4*j+1) * NVOX + n]);
        __builtin_nontemporal_store(facc[j].z * invd, &out[(size_t)(4*j+2) * NVOX + n]);
        __builtin_nontemporal_store(facc[j].w * invd, &out[(size_t)(4*j+3) * NVOX + n]);
    }
    __builtin_nontemporal_store(vsum  * invd, &out[(size_t)CCH*NVOX + n]);
    __builtin_nontemporal_store(zsum  * invd, &out[(size_t)CCH*NVOX + NVOX + n]);
    __builtin_nontemporal_store(ndsum * invd, &out[(size_t)CCH*NVOX + 2*(size_t)NVOX + n]);
}

// ---------------- fallback: round-1 kernel (original layouts) --------------------
__global__ __launch_bounds__(256) void mvmap_main(
    const float* __restrict__ img_feats,
    const float* __restrict__ variances,
    const float* __restrict__ render_depth,
    const float* __restrict__ coords,
    const float* __restrict__ Ps,
    const float* __restrict__ Ks,
    float* __restrict__ out)
{
    __shared__ float sW2C[NCAMS][12];
    __shared__ float sK[NCAMS][9];

    if (threadIdx.x < NCAMS) {
        int b = threadIdx.x;
        const float* P = Ps + b * 16;
        float r00=P[0], r01=P[1], r02=P[2],  tx=P[3];
        float r10=P[4], r11=P[5], r12=P[6],  ty=P[7];
        float r20=P[8], r21=P[9], r22=P[10], tz=P[11];
        float det = r00*(r11*r22 - r12*r21)
                  - r01*(r10*r22 - r12*r20)
                  + r02*(r10*r21 - r11*r20);
        float id = 1.0f / det;
        float i00 =  (r11*r22 - r12*r21) * id;
        float i01 = -(r01*r22 - r02*r21) * id;
        float i02 =  (r01*r12 - r02*r11) * id;
        float i10 = -(r10*r22 - r12*r20) * id;
        float i11 =  (r00*r22 - r02*r20) * id;
        float i12 = -(r00*r12 - r02*r10) * id;
        float i20 =  (r10*r21 - r11*r20) * id;
        float i21 = -(r00*r21 - r01*r20) * id;
        float i22 =  (r00*r11 - r01*r10) * id;
        sW2C[b][0]=i00; sW2C[b][1]=i01; sW2C[b][2] =i02; sW2C[b][3] =-(i00*tx + i01*ty + i02*tz);
        sW2C[b][4]=i10; sW2C[b][5]=i11; sW2C[b][6] =i12; sW2C[b][7] =-(i10*tx + i11*ty + i12*tz);
        sW2C[b][8]=i20; sW2C[b][9]=i21; sW2C[b][10]=i22; sW2C[b][11]=-(i20*tx + i21*ty + i22*tz);
        #pragma unroll
        for (int j = 0; j < 9; j++) sK[b][j] = Ks[b*9 + j];
    }
    __syncthreads();

    int n = blockIdx.x * blockDim.x + threadIdx.x;
    if (n >= NVOX) return;

    float px = coords[3*n + 0];
    float pz = coords[3*n + 1];
    float ph = coords[3*n + 2];

    float fsum[CCH];
    #pragma unroll
    for (int c = 0; c < CCH; c++) fsum[c] = 0.0f;
    float wsum = 0.0f, vsum = 0.0f, ndsum = 0.0f, zsum = 0.0f;

    for (int b = 0; b < NCAMS; b++) {
        float cx = sW2C[b][0]*px + sW2C[b][1]*pz + sW2C[b][2] *ph + sW2C[b][3];
        float cy = sW2C[b][4]*px + sW2C[b][5]*pz + sW2C[b][6] *ph + sW2C[b][7];
        float cz = sW2C[b][8]*px + sW2C[b][9]*pz + sW2C[b][10]*ph + sW2C[b][11];
        float u0 = sK[b][0]*cx + sK[b][1]*cy + sK[b][2]*cz;
        float v0 = sK[b][3]*cx + sK[b][4]*cy + sK[b][5]*cz;
        float zc = sK[b][6]*cx + sK[b][7]*cy + sK[b][8]*cz;
        float zsafe = (fabsf(zc) < 1e-6f) ? 1e-6f : zc;
        float u = u0 / zsafe;
        float v = v0 / zsafe;
        bool mask = (zc > 1e-3f) && (u >= 0.0f) && (u < (float)IMG_W)
                                 && (v >= 0.0f) && (v < (float)IMG_H);
        if (!mask) continue;

        wsum += 1.0f;
        zsum += zc;
        {
            float xf = v * 0.25f - 0.5f;
            float yf = u * 0.25f - 0.5f;
            float x0f = floorf(xf), y0f = floorf(yf);
            float wx = xf - x0f, wy = yf - y0f;
            int x0 = (int)x0f, y0 = (int)y0f;
            float vx0 = (x0   >= 0 && x0   < FXV) ? 1.0f : 0.0f;
            float vx1 = (x0+1 >= 0 && x0+1 < FXV) ? 1.0f : 0.0f;
            float vy0 = (y0   >= 0 && y0   < FZV) ? 1.0f : 0.0f;
            float vy1 = (y0+1 >= 0 && y0+1 < FZV) ? 1.0f : 0.0f;
            float w00 = (1.0f-wx)*(1.0f-wy)*vx0*vy0;
            float w10 = wx*(1.0f-wy)*vx1*vy0;
            float w01 = (1.0f-wx)*wy*vx0*vy1;
            float w11 = wx*wy*vx1*vy1;
            int xi0 = min(max(x0,   0), FXV-1), xi1 = min(max(x0+1, 0), FXV-1);
            int yi0 = min(max(y0,   0), FZV-1), yi1 = min(max(y0+1, 0), FZV-1);
            int o00 = xi0*FZV + yi0, o01 = xi0*FZV + yi1;
            int o10 = xi1*FZV + yi0, o11 = xi1*FZV + yi1;
            const float* p = img_feats + (size_t)b * (CCH*FXV*FZV);
            #pragma unroll
            for (int c = 0; c < CCH; c++) {
                const float* pc = p + c * (FXV*FZV);
                fsum[c] += w00*pc[o00] + w01*pc[o01] + w10*pc[o10] + w11*pc[o11];
            }
        }
        {
            float xf = v - 0.5f;
            float yf = u - 0.5f;
            float x0f = floorf(xf), y0f = floorf(yf);
            float wx = xf - x0f, wy = yf - y0f;
            int x0 = (int)x0f, y0 = (int)y0f;
            float vx0 = (x0   >= 0 && x0   < IMG_H) ? 1.0f : 0.0f;
            float vx1 = (x0+1 >= 0 && x0+1 < IMG_H) ? 1.0f : 0.0f;
            float vy0 = (y0   >= 0 && y0   < IMG_W) ? 1.0f : 0.0f;
            float vy1 = (y0+1 >= 0 && y0+1 < IMG_W) ? 1.0f : 0.0f;
            float w00 = (1.0f-wx)*(1.0f-wy)*vx0*vy0;
            float w10 = wx*(1.0f-wy)*vx1*vy0;
            float w01 = (1.0f-wx)*wy*vx0*vy1;
            float w11 = wx*wy*vx1*vy1;
            int xi0 = min(max(x0,   0), IMG_H-1), xi1 = min(max(x0+1, 0), IMG_H-1);
            int yi0 = min(max(y0,   0), IMG_W-1), yi1 = min(max(y0+1, 0), IMG_W-1);
            int o00 = xi0*IMG_W + yi0, o01 = xi0*IMG_W + yi1;
            int o10 = xi1*IMG_W + yi0, o11 = xi1*IMG_W + yi1;
            const float* pv = variances    + (size_t)b * (IMG_H*IMG_W);
            const float* pd = render_depth + (size_t)b * (IMG_H*IMG_W);
            vsum  += w00*pv[o00] + w01*pv[o01] + w10*pv[o10] + w11*pv[o11];
            ndsum += w00*pd[o00] + w01*pd[o01] + w10*pd[o10] + w11*pd[o11];
        }
    }

    float invd = 1.0f / (wsum + 1e-6f);
    #pragma unroll
    for (int c = 0; c < CCH; c++) out[(size_t)c * NVOX + n] = fsum[c] * invd;
    out[(size_t)CCH*NVOX + n]              = vsum  * invd;
    out[(size_t)CCH*NVOX + NVOX + n]       = zsum  * invd;
    out[(size_t)CCH*NVOX + 2*(size_t)NVOX + n] = ndsum * invd;
}

extern "C" void kernel_launch(void* const* d_in, const int* in_sizes, int n_in,
                              void* d_out, int out_size, void* d_ws, size_t ws_size,
                              hipStream_t stream) {
    const float* img_feats    = (const float*)d_in[0];
    const float* variances    = (const float*)d_in[1];
    const float* render_depth = (const float*)d_in[2];
    const float* coords       = (const float*)d_in[3];
    const float* Ps           = (const float*)d_in[4];
    const float* Ks           = (const float*)d_in[5];
    float* out = (float*)d_out;

    if (ws_size >= WS_NEED_BYTES) {
        float* feats_t = (float*)d_ws;
        float* vd_t    = feats_t + FEATS_T_ELEMS;
        {
            int n = NCAMS * FXV * FZV;
            hipLaunchKernelGGL(prep_feats_t, dim3((n + 255) / 256), dim3(256), 0, stream,
                               img_feats, feats_t);
        }
        {
            int n = NCAMS * IMG_H * IMG_W;
            hipLaunchKernelGGL(prep_vd_t, dim3((n + 255) / 256), dim3(256), 0, stream,
                               variances, render_depth, vd_t);
        }
        hipLaunchKernelGGL(mvmap_fast, dim3(NVOX / 256), dim3(256), 0, stream,
                           feats_t, vd_t, coords, Ps, Ks, out);
    } else {
        hipLaunchKernelGGL(mvmap_main, dim3(NVOX / 256), dim3(256), 0, stream,
                           img_feats, variances, render_depth, coords, Ps, Ks, out);
    }
}

// Round 3
// 51.500 us; speedup vs baseline: 1.2351x; 1.2351x over previous
//
#include <hip/hip_runtime.h>
#include <math.h>

#define NCAMS 6
#define CCH   32
#define YY    8
#define XX    256
#define ZZ    256
#define NVOX  (YY*XX*ZZ)        // 524288
#define IMG_H 224
#define IMG_W 400
#define FXV   56
#define FZV   100

#define NF (NCAMS*FXV*FZV)          // 33600 feat pixels
#define NV (NCAMS*IMG_H*IMG_W)      // 537600 vd pixels
#define FEATS_T_ELEMS (NF*CCH)      // 1,075,200
#define VD_T_ELEMS    (NV*2)        // 1,075,200
#define WS_NEED_BYTES ((size_t)(FEATS_T_ELEMS + VD_T_ELEMS) * 4)

// ---------------- fused prep: feats [6,32,56,100]->[6,56,100,32]; var+dep -> [6,224,400,2]
__global__ __launch_bounds__(256) void prep_all(
    const float* __restrict__ src_f, const float* __restrict__ var,
    const float* __restrict__ dep, float* __restrict__ dst_f,
    float* __restrict__ dst_vd)
{
    int t = blockIdx.x * 256 + threadIdx.x;
    if (t < NF) {
        int b = t / (FXV * FZV);
        int r = t - b * (FXV * FZV);
        float4* d4 = (float4*)(dst_f + (size_t)t * CCH);
        #pragma unroll
        for (int j = 0; j < CCH / 4; j++) {
            float4 v;
            v.x = src_f[(size_t)(b * CCH + 4*j + 0) * (FXV*FZV) + r];
            v.y = src_f[(size_t)(b * CCH + 4*j + 1) * (FXV*FZV) + r];
            v.z = src_f[(size_t)(b * CCH + 4*j + 2) * (FXV*FZV) + r];
            v.w = src_f[(size_t)(b * CCH + 4*j + 3) * (FXV*FZV) + r];
            d4[j] = v;
        }
    } else {
        int u = t - NF;
        if (u < NV) ((float2*)dst_vd)[u] = make_float2(var[u], dep[u]);
    }
}

// ---------------- main: 4 threads per voxel (8 channels each), dynamic balancing ----
__global__ __launch_bounds__(256) void mvmap_fast(
    const float* __restrict__ feats_t,   // [6,56,100,32]
    const float* __restrict__ vd_t,      // [6,224,400,2]
    const float* __restrict__ coords,    // [1,524288,3]  (px, pz, h)
    const float* __restrict__ Ps,        // [6,4,4] cam2world
    const float* __restrict__ Ks,        // [6,3,3]
    float* __restrict__ out)
{
    __shared__ float sW2C[NCAMS][12];
    __shared__ float sK[NCAMS][9];

    if (threadIdx.x < NCAMS) {
        int b = threadIdx.x;
        const float* P = Ps + b * 16;
        float r00=P[0], r01=P[1], r02=P[2],  tx=P[3];
        float r10=P[4], r11=P[5], r12=P[6],  ty=P[7];
        float r20=P[8], r21=P[9], r22=P[10], tz=P[11];
        float det = r00*(r11*r22 - r12*r21)
                  - r01*(r10*r22 - r12*r20)
                  + r02*(r10*r21 - r11*r20);
        float id = 1.0f / det;
        float i00 =  (r11*r22 - r12*r21) * id;
        float i01 = -(r01*r22 - r02*r21) * id;
        float i02 =  (r01*r12 - r02*r11) * id;
        float i10 = -(r10*r22 - r12*r20) * id;
        float i11 =  (r00*r22 - r02*r20) * id;
        float i12 = -(r00*r12 - r02*r10) * id;
        float i20 =  (r10*r21 - r11*r20) * id;
        float i21 = -(r00*r21 - r01*r20) * id;
        float i22 =  (r00*r11 - r01*r10) * id;
        sW2C[b][0]=i00; sW2C[b][1]=i01; sW2C[b][2] =i02; sW2C[b][3] =-(i00*tx + i01*ty + i02*tz);
        sW2C[b][4]=i10; sW2C[b][5]=i11; sW2C[b][6] =i12; sW2C[b][7] =-(i10*tx + i11*ty + i12*tz);
        sW2C[b][8]=i20; sW2C[b][9]=i21; sW2C[b][10]=i22; sW2C[b][11]=-(i20*tx + i21*ty + i22*tz);
        #pragma unroll
        for (int j = 0; j < 9; j++) sK[b][j] = Ks[b*9 + j];
    }
    __syncthreads();

    int t = blockIdx.x * 256 + threadIdx.x;   // 0 .. 4*NVOX-1
    int n = t >> 2;                           // voxel
    int j = t & 3;                            // channel group (8 channels)

    float px = coords[3*n + 0];
    float pz = coords[3*n + 1];
    float ph = coords[3*n + 2];

    float4 f0 = make_float4(0.f,0.f,0.f,0.f);
    float4 f1 = make_float4(0.f,0.f,0.f,0.f);
    float wsum = 0.0f, vsum = 0.0f, ndsum = 0.0f, zsum = 0.0f;

    for (int b = 0; b < NCAMS; b++) {
        float cx = sW2C[b][0]*px + sW2C[b][1]*pz + sW2C[b][2] *ph + sW2C[b][3];
        float cy = sW2C[b][4]*px + sW2C[b][5]*pz + sW2C[b][6] *ph + sW2C[b][7];
        float cz = sW2C[b][8]*px + sW2C[b][9]*pz + sW2C[b][10]*ph + sW2C[b][11];
        float u0 = sK[b][0]*cx + sK[b][1]*cy + sK[b][2]*cz;
        float v0 = sK[b][3]*cx + sK[b][4]*cy + sK[b][5]*cz;
        float zc = sK[b][6]*cx + sK[b][7]*cy + sK[b][8]*cz;
        float zsafe = (fabsf(zc) < 1e-6f) ? 1e-6f : zc;
        float u = u0 / zsafe;
        float v = v0 / zsafe;
        bool mask = (zc > 1e-3f) && (u >= 0.0f) && (u < (float)IMG_W)
                                 && (v >= 0.0f) && (v < (float)IMG_H);
        if (!mask) continue;

        wsum += 1.0f;
        zsum += zc;

        // ---- features: channels-last, this thread's 8 channels (2 float4 per tap) ----
        {
            float xf = v * 0.25f - 0.5f;      // width dim (56)
            float yf = u * 0.25f - 0.5f;      // height dim (100)
            float x0f = floorf(xf), y0f = floorf(yf);
            float wx = xf - x0f, wy = yf - y0f;
            int x0 = (int)x0f, y0 = (int)y0f;
            float vx0 = (x0   >= 0 && x0   < FXV) ? 1.0f : 0.0f;
            float vx1 = (x0+1 >= 0 && x0+1 < FXV) ? 1.0f : 0.0f;
            float vy0 = (y0   >= 0 && y0   < FZV) ? 1.0f : 0.0f;
            float vy1 = (y0+1 >= 0 && y0+1 < FZV) ? 1.0f : 0.0f;
            float w00 = (1.0f-wx)*(1.0f-wy)*vx0*vy0;
            float w10 = wx*(1.0f-wy)*vx1*vy0;
            float w01 = (1.0f-wx)*wy*vx0*vy1;
            float w11 = wx*wy*vx1*vy1;
            int xi0 = min(max(x0,   0), FXV-1), xi1 = min(max(x0+1, 0), FXV-1);
            int yi0 = min(max(y0,   0), FZV-1), yi1 = min(max(y0+1, 0), FZV-1);
            const float* base = feats_t + (size_t)b * (FXV*FZV*CCH) + j * 8;
            const float4* p00 = (const float4*)(base + (size_t)(xi0*FZV + yi0)*CCH);
            const float4* p01 = (const float4*)(base + (size_t)(xi0*FZV + yi1)*CCH);
            const float4* p10 = (const float4*)(base + (size_t)(xi1*FZV + yi0)*CCH);
            const float4* p11 = (const float4*)(base + (size_t)(xi1*FZV + yi1)*CCH);
            {
                float4 a = p00[0], b2 = p01[0], c2 = p10[0], d2 = p11[0];
                f0.x += w00*a.x + w01*b2.x + w10*c2.x + w11*d2.x;
                f0.y += w00*a.y + w01*b2.y + w10*c2.y + w11*d2.y;
                f0.z += w00*a.z + w01*b2.z + w10*c2.z + w11*d2.z;
                f0.w += w00*a.w + w01*b2.w + w10*c2.w + w11*d2.w;
            }
            {
                float4 a = p00[1], b2 = p01[1], c2 = p10[1], d2 = p11[1];
                f1.x += w00*a.x + w01*b2.x + w10*c2.x + w11*d2.x;
                f1.y += w00*a.y + w01*b2.y + w10*c2.y + w11*d2.y;
                f1.z += w00*a.z + w01*b2.z + w10*c2.z + w11*d2.z;
                f1.w += w00*a.w + w01*b2.w + w10*c2.w + w11*d2.w;
            }
        }

        // ---- variance+depth (redundant across the 4 lanes; loads broadcast) ----
        {
            float xf = v - 0.5f;
            float yf = u - 0.5f;
            float x0f = floorf(xf), y0f = floorf(yf);
            float wx = xf - x0f, wy = yf - y0f;
            int x0 = (int)x0f, y0 = (int)y0f;
            float vx0 = (x0   >= 0 && x0   < IMG_H) ? 1.0f : 0.0f;
            float vx1 = (x0+1 >= 0 && x0+1 < IMG_H) ? 1.0f : 0.0f;
            float vy0 = (y0   >= 0 && y0   < IMG_W) ? 1.0f : 0.0f;
            float vy1 = (y0+1 >= 0 && y0+1 < IMG_W) ? 1.0f : 0.0f;
            float w00 = (1.0f-wx)*(1.0f-wy)*vx0*vy0;
            float w10 = wx*(1.0f-wy)*vx1*vy0;
            float w01 = (1.0f-wx)*wy*vx0*vy1;
            float w11 = wx*wy*vx1*vy1;
            int xi0 = min(max(x0,   0), IMG_H-1), xi1 = min(max(x0+1, 0), IMG_H-1);
            int yi0 = min(max(y0,   0), IMG_W-1), yi1 = min(max(y0+1, 0), IMG_W-1);
            const float2* pv = (const float2*)(vd_t) + (size_t)b * (IMG_H*IMG_W);
            float2 t00 = pv[xi0*IMG_W + yi0], t01 = pv[xi0*IMG_W + yi1];
            float2 t10 = pv[xi1*IMG_W + yi0], t11 = pv[xi1*IMG_W + yi1];
            vsum  += w00*t00.x + w01*t01.x + w10*t10.x + w11*t11.x;
            ndsum += w00*t00.y + w01*t01.y + w10*t10.y + w11*t11.y;
        }
    }

    float invd = 1.0f / (wsum + 1e-6f);
    #pragma unroll
    for (int k = 0; k < 4; k++) {
        float fv = (&f0.x)[k] * invd;
        __builtin_nontemporal_store(fv, &out[(size_t)(8*j + k) * NVOX + n]);
    }
    #pragma unroll
    for (int k = 0; k < 4; k++) {
        float fv = (&f1.x)[k] * invd;
        __builtin_nontemporal_store(fv, &out[(size_t)(8*j + 4 + k) * NVOX + n]);
    }
    if (j == 0) {
        __builtin_nontemporal_store(vsum  * invd, &out[(size_t)CCH*NVOX + n]);
        __builtin_nontemporal_store(zsum  * invd, &out[(size_t)CCH*NVOX + NVOX + n]);
        __builtin_nontemporal_store(ndsum * invd, &out[(size_t)CCH*NVOX + 2*(size_t)NVOX + n]);
    }
}

// ---------------- fallback (round-1 style, original layouts) --------------------
__global__ __launch_bounds__(256) void mvmap_main(
    const float* __restrict__ img_feats,
    const float* __restrict__ variances,
    const float* __restrict__ render_depth,
    const float* __restrict__ coords,
    const float* __restrict__ Ps,
    const float* __restrict__ Ks,
    float* __restrict__ out)
{
    __shared__ float sW2C[NCAMS][12];
    __shared__ float sK[NCAMS][9];

    if (threadIdx.x < NCAMS) {
        int b = threadIdx.x;
        const float* P = Ps + b * 16;
        float r00=P[0], r01=P[1], r02=P[2],  tx=P[3];
        float r10=P[4], r11=P[5], r12=P[6],  ty=P[7];
        float r20=P[8], r21=P[9], r22=P[10], tz=P[11];
        float det = r00*(r11*r22 - r12*r21)
                  - r01*(r10*r22 - r12*r20)
                  + r02*(r10*r21 - r11*r20);
        float id = 1.0f / det;
        float i00 =  (r11*r22 - r12*r21) * id;
        float i01 = -(r01*r22 - r02*r21) * id;
        float i02 =  (r01*r12 - r02*r11) * id;
        float i10 = -(r10*r22 - r12*r20) * id;
        float i11 =  (r00*r22 - r02*r20) * id;
        float i12 = -(r00*r12 - r02*r10) * id;
        float i20 =  (r10*r21 - r11*r20) * id;
        float i21 = -(r00*r21 - r01*r20) * id;
        float i22 =  (r00*r11 - r01*r10) * id;
        sW2C[b][0]=i00; sW2C[b][1]=i01; sW2C[b][2] =i02; sW2C[b][3] =-(i00*tx + i01*ty + i02*tz);
        sW2C[b][4]=i10; sW2C[b][5]=i11; sW2C[b][6] =i12; sW2C[b][7] =-(i10*tx + i11*ty + i12*tz);
        sW2C[b][8]=i20; sW2C[b][9]=i21; sW2C[b][10]=i22; sW2C[b][11]=-(i20*tx + i21*ty + i22*tz);
        #pragma unroll
        for (int jj = 0; jj < 9; jj++) sK[b][jj] = Ks[b*9 + jj];
    }
    __syncthreads();

    int n = blockIdx.x * blockDim.x + threadIdx.x;
    if (n >= NVOX) return;

    float px = coords[3*n + 0];
    float pz = coords[3*n + 1];
    float ph = coords[3*n + 2];

    float fsum[CCH];
    #pragma unroll
    for (int c = 0; c < CCH; c++) fsum[c] = 0.0f;
    float wsum = 0.0f, vsum = 0.0f, ndsum = 0.0f, zsum = 0.0f;

    for (int b = 0; b < NCAMS; b++) {
        float cx = sW2C[b][0]*px + sW2C[b][1]*pz + sW2C[b][2] *ph + sW2C[b][3];
        float cy = sW2C[b][4]*px + sW2C[b][5]*pz + sW2C[b][6] *ph + sW2C[b][7];
        float cz = sW2C[b][8]*px + sW2C[b][9]*pz + sW2C[b][10]*ph + sW2C[b][11];
        float u0 = sK[b][0]*cx + sK[b][1]*cy + sK[b][2]*cz;
        float v0 = sK[b][3]*cx + sK[b][4]*cy + sK[b][5]*cz;
        float zc = sK[b][6]*cx + sK[b][7]*cy + sK[b][8]*cz;
        float zsafe = (fabsf(zc) < 1e-6f) ? 1e-6f : zc;
        float u = u0 / zsafe;
        float v = v0 / zsafe;
        bool mask = (zc > 1e-3f) && (u >= 0.0f) && (u < (float)IMG_W)
                                 && (v >= 0.0f) && (v < (float)IMG_H);
        if (!mask) continue;

        wsum += 1.0f;
        zsum += zc;
        {
            float xf = v * 0.25f - 0.5f;
            float yf = u * 0.25f - 0.5f;
            float x0f = floorf(xf), y0f = floorf(yf);
            float wx = xf - x0f, wy = yf - y0f;
            int x0 = (int)x0f, y0 = (int)y0f;
            float vx0 = (x0   >= 0 && x0   < FXV) ? 1.0f : 0.0f;
            float vx1 = (x0+1 >= 0 && x0+1 < FXV) ? 1.0f : 0.0f;
            float vy0 = (y0   >= 0 && y0   < FZV) ? 1.0f : 0.0f;
            float vy1 = (y0+1 >= 0 && y0+1 < FZV) ? 1.0f : 0.0f;
            float w00 = (1.0f-wx)*(1.0f-wy)*vx0*vy0;
            float w10 = wx*(1.0f-wy)*vx1*vy0;
            float w01 = (1.0f-wx)*wy*vx0*vy1;
            float w11 = wx*wy*vx1*vy1;
            int xi0 = min(max(x0,   0), FXV-1), xi1 = min(max(x0+1, 0), FXV-1);
            int yi0 = min(max(y0,   0), FZV-1), yi1 = min(max(y0+1, 0), FZV-1);
            int o00 = xi0*FZV + yi0, o01 = xi0*FZV + yi1;
            int o10 = xi1*FZV + yi0, o11 = xi1*FZV + yi1;
            const float* p = img_feats + (size_t)b * (CCH*FXV*FZV);
            #pragma unroll
            for (int c = 0; c < CCH; c++) {
                const float* pc = p + c * (FXV*FZV);
                fsum[c] += w00*pc[o00] + w01*pc[o01] + w10*pc[o10] + w11*pc[o11];
            }
        }
        {
            float xf = v - 0.5f;
            float yf = u - 0.5f;
            float x0f = floorf(xf), y0f = floorf(yf);
            float wx = xf - x0f, wy = yf - y0f;
            int x0 = (int)x0f, y0 = (int)y0f;
            float vx0 = (x0   >= 0 && x0   < IMG_H) ? 1.0f : 0.0f;
            float vx1 = (x0+1 >= 0 && x0+1 < IMG_H) ? 1.0f : 0.0f;
            float vy0 = (y0   >= 0 && y0   < IMG_W) ? 1.0f : 0.0f;
            float vy1 = (y0+1 >= 0 && y0+1 < IMG_W) ? 1.0f : 0.0f;
            float w00 = (1.0f-wx)*(1.0f-wy)*vx0*vy0;
            float w10 = wx*(1.0f-wy)*vx1*vy0;
            float w01 = (1.0f-wx)*wy*vx0*vy1;
            float w11 = wx*wy*vx1*vy1;
            int xi0 = min(max(x0,   0), IMG_H-1), xi1 = min(max(x0+1, 0), IMG_H-1);
            int yi0 = min(max(y0,   0), IMG_W-1), yi1 = min(max(y0+1, 0), IMG_W-1);
            int o00 = xi0*IMG_W + yi0, o01 = xi0*IMG_W + yi1;
            int o10 = xi1*IMG_W + yi0, o11 = xi1*IMG_W + yi1;
            const float* pv = variances    + (size_t)b * (IMG_H*IMG_W);
            const float* pd = render_depth + (size_t)b * (IMG_H*IMG_W);
            vsum  += w00*pv[o00] + w01*pv[o01] + w10*pv[o10] + w11*pv[o11];
            ndsum += w00*pd[o00] + w01*pd[o01] + w10*pd[o10] + w11*pd[o11];
        }
    }

    float invd = 1.0f / (wsum + 1e-6f);
    #pragma unroll
    for (int c = 0; c < CCH; c++) out[(size_t)c * NVOX + n] = fsum[c] * invd;
    out[(size_t)CCH*NVOX + n]              = vsum  * invd;
    out[(size_t)CCH*NVOX + NVOX + n]       = zsum  * invd;
    out[(size_t)CCH*NVOX + 2*(size_t)NVOX + n] = ndsum * invd;
}

extern "C" void kernel_launch(void* const* d_in, const int* in_sizes, int n_in,
                              void* d_out, int out_size, void* d_ws, size_t ws_size,
                              hipStream_t stream) {
    const float* img_feats    = (const float*)d_in[0];
    const float* variances    = (const float*)d_in[1];
    const float* render_depth = (const float*)d_in[2];
    const float* coords       = (const float*)d_in[3];
    const float* Ps           = (const float*)d_in[4];
    const float* Ks           = (const float*)d_in[5];
    float* out = (float*)d_out;

    if (ws_size >= WS_NEED_BYTES) {
        float* feats_t = (float*)d_ws;
        float* vd_t    = feats_t + FEATS_T_ELEMS;
        {
            int total = NF + NV;
            hipLaunchKernelGGL(prep_all, dim3((total + 255) / 256), dim3(256), 0, stream,
                               img_feats, variances, render_depth, feats_t, vd_t);
        }
        hipLaunchKernelGGL(mvmap_fast, dim3((4 * NVOX) / 256), dim3(256), 0, stream,
                           feats_t, vd_t, coords, Ps, Ks, out);
    } else {
        hipLaunchKernelGGL(mvmap_main, dim3(NVOX / 256), dim3(256), 0, stream,
                           img_feats, variances, render_depth, coords, Ps, Ks, out);
    }
}

// Round 4
// 47.298 us; speedup vs baseline: 1.3448x; 1.0888x over previous
//
#include <hip/hip_runtime.h>
#include <math.h>

#define NCAMS 6
#define CCH   32
#define YY    8
#define XX    256
#define ZZ    256
#define NVOX  (YY*XX*ZZ)        // 524288
#define IMG_H 224
#define IMG_W 400
#define FXV   56
#define FZV   100

#define NF (NCAMS*FXV*FZV)          // 33600 feat pixels
#define NV (NCAMS*IMG_H*IMG_W)      // 537600 vd pixels
#define FEATS_T_ELEMS (NF*CCH)      // 1,075,200
#define VD_T_ELEMS    (NV*2)        // 1,075,200
#define WS_NEED_BYTES ((size_t)(FEATS_T_ELEMS + VD_T_ELEMS) * 4)

// ---------------- fused prep: feats [6,32,56,100]->[6,56,100,32]; var+dep -> [6,224,400,2]
__global__ __launch_bounds__(256) void prep_all(
    const float* __restrict__ src_f, const float* __restrict__ var,
    const float* __restrict__ dep, float* __restrict__ dst_f,
    float* __restrict__ dst_vd)
{
    int t = blockIdx.x * 256 + threadIdx.x;
    if (t < NF) {
        int b = t / (FXV * FZV);
        int r = t - b * (FXV * FZV);
        float4* d4 = (float4*)(dst_f + (size_t)t * CCH);
        #pragma unroll
        for (int j = 0; j < CCH / 4; j++) {
            float4 v;
            v.x = src_f[(size_t)(b * CCH + 4*j + 0) * (FXV*FZV) + r];
            v.y = src_f[(size_t)(b * CCH + 4*j + 1) * (FXV*FZV) + r];
            v.z = src_f[(size_t)(b * CCH + 4*j + 2) * (FXV*FZV) + r];
            v.w = src_f[(size_t)(b * CCH + 4*j + 3) * (FXV*FZV) + r];
            d4[j] = v;
        }
    } else {
        int u = t - NF;
        if (u < NV) ((float2*)dst_vd)[u] = make_float2(var[u], dep[u]);
    }
}

// ---------------- main: 2 lanes per voxel (16 channels each), wave = 32 voxels ----
__global__ __launch_bounds__(128) void mvmap_fast(
    const float* __restrict__ feats_t,   // [6,56,100,32]
    const float* __restrict__ vd_t,      // [6,224,400,2]
    const float* __restrict__ coords,    // [1,524288,3]  (px, pz, h)
    const float* __restrict__ Ps,        // [6,4,4] cam2world
    const float* __restrict__ Ks,        // [6,3,3]
    float* __restrict__ out)
{
    __shared__ float sW2C[NCAMS][12];
    __shared__ float sK[NCAMS][9];

    if (threadIdx.x < NCAMS) {
        int b = threadIdx.x;
        const float* P = Ps + b * 16;
        float r00=P[0], r01=P[1], r02=P[2],  tx=P[3];
        float r10=P[4], r11=P[5], r12=P[6],  ty=P[7];
        float r20=P[8], r21=P[9], r22=P[10], tz=P[11];
        float det = r00*(r11*r22 - r12*r21)
                  - r01*(r10*r22 - r12*r20)
                  + r02*(r10*r21 - r11*r20);
        float id = 1.0f / det;
        float i00 =  (r11*r22 - r12*r21) * id;
        float i01 = -(r01*r22 - r02*r21) * id;
        float i02 =  (r01*r12 - r02*r11) * id;
        float i10 = -(r10*r22 - r12*r20) * id;
        float i11 =  (r00*r22 - r02*r20) * id;
        float i12 = -(r00*r12 - r02*r10) * id;
        float i20 =  (r10*r21 - r11*r20) * id;
        float i21 = -(r00*r21 - r01*r20) * id;
        float i22 =  (r00*r11 - r01*r10) * id;
        sW2C[b][0]=i00; sW2C[b][1]=i01; sW2C[b][2] =i02; sW2C[b][3] =-(i00*tx + i01*ty + i02*tz);
        sW2C[b][4]=i10; sW2C[b][5]=i11; sW2C[b][6] =i12; sW2C[b][7] =-(i10*tx + i11*ty + i12*tz);
        sW2C[b][8]=i20; sW2C[b][9]=i21; sW2C[b][10]=i22; sW2C[b][11]=-(i20*tx + i21*ty + i22*tz);
        #pragma unroll
        for (int j = 0; j < 9; j++) sK[b][j] = Ks[b*9 + j];
    }
    __syncthreads();

    int t = blockIdx.x * 128 + threadIdx.x;   // 0 .. 2*NVOX-1
    int n = t >> 1;                           // voxel
    int j = t & 1;                            // channel half (16 channels)

    float px = coords[3*n + 0];
    float pz = coords[3*n + 1];
    float ph = coords[3*n + 2];

    float4 facc[4];
    #pragma unroll
    for (int q = 0; q < 4; q++) facc[q] = make_float4(0.f,0.f,0.f,0.f);
    float wsum = 0.0f, vsum = 0.0f, ndsum = 0.0f, zsum = 0.0f;

    for (int b = 0; b < NCAMS; b++) {
        float cx = sW2C[b][0]*px + sW2C[b][1]*pz + sW2C[b][2] *ph + sW2C[b][3];
        float cy = sW2C[b][4]*px + sW2C[b][5]*pz + sW2C[b][6] *ph + sW2C[b][7];
        float cz = sW2C[b][8]*px + sW2C[b][9]*pz + sW2C[b][10]*ph + sW2C[b][11];
        float u0 = sK[b][0]*cx + sK[b][1]*cy + sK[b][2]*cz;
        float v0 = sK[b][3]*cx + sK[b][4]*cy + sK[b][5]*cz;
        float zc = sK[b][6]*cx + sK[b][7]*cy + sK[b][8]*cz;
        float zsafe = (fabsf(zc) < 1e-6f) ? 1e-6f : zc;
        float u = u0 / zsafe;                 // exact IEEE divide: mask must be bit-identical
        float v = v0 / zsafe;
        bool mask = (zc > 1e-3f) && (u >= 0.0f) && (u < (float)IMG_W)
                                 && (v >= 0.0f) && (v < (float)IMG_H);
        if (!mask) continue;

        wsum += 1.0f;
        zsum += zc;

        // ---- features: channels-last, this thread's 16 channels (4 float4 per tap) ----
        {
            float xf = v * 0.25f - 0.5f;      // width dim (56)
            float yf = u * 0.25f - 0.5f;      // height dim (100)
            float x0f = floorf(xf), y0f = floorf(yf);
            float wx = xf - x0f, wy = yf - y0f;
            int x0 = (int)x0f, y0 = (int)y0f;
            float vx0 = (x0   >= 0 && x0   < FXV) ? 1.0f : 0.0f;
            float vx1 = (x0+1 >= 0 && x0+1 < FXV) ? 1.0f : 0.0f;
            float vy0 = (y0   >= 0 && y0   < FZV) ? 1.0f : 0.0f;
            float vy1 = (y0+1 >= 0 && y0+1 < FZV) ? 1.0f : 0.0f;
            float w00 = (1.0f-wx)*(1.0f-wy)*vx0*vy0;
            float w10 = wx*(1.0f-wy)*vx1*vy0;
            float w01 = (1.0f-wx)*wy*vx0*vy1;
            float w11 = wx*wy*vx1*vy1;
            int xi0 = min(max(x0,   0), FXV-1), xi1 = min(max(x0+1, 0), FXV-1);
            int yi0 = min(max(y0,   0), FZV-1), yi1 = min(max(y0+1, 0), FZV-1);
            const float* base = feats_t + (size_t)b * (FXV*FZV*CCH) + j * 16;
            const float4* p00 = (const float4*)(base + (size_t)(xi0*FZV + yi0)*CCH);
            const float4* p01 = (const float4*)(base + (size_t)(xi0*FZV + yi1)*CCH);
            const float4* p10 = (const float4*)(base + (size_t)(xi1*FZV + yi0)*CCH);
            const float4* p11 = (const float4*)(base + (size_t)(xi1*FZV + yi1)*CCH);
            #pragma unroll
            for (int q = 0; q < 4; q++) {
                float4 a = p00[q], b2 = p01[q], c2 = p10[q], d2 = p11[q];
                facc[q].x += w00*a.x + w01*b2.x + w10*c2.x + w11*d2.x;
                facc[q].y += w00*a.y + w01*b2.y + w10*c2.y + w11*d2.y;
                facc[q].z += w00*a.z + w01*b2.z + w10*c2.z + w11*d2.z;
                facc[q].w += w00*a.w + w01*b2.w + w10*c2.w + w11*d2.w;
            }
        }

        // ---- variance+depth (computed by both j-lanes; only j==0 stores) ----
        {
            float xf = v - 0.5f;
            float yf = u - 0.5f;
            float x0f = floorf(xf), y0f = floorf(yf);
            float wx = xf - x0f, wy = yf - y0f;
            int x0 = (int)x0f, y0 = (int)y0f;
            float vx0 = (x0   >= 0 && x0   < IMG_H) ? 1.0f : 0.0f;
            float vx1 = (x0+1 >= 0 && x0+1 < IMG_H) ? 1.0f : 0.0f;
            float vy0 = (y0   >= 0 && y0   < IMG_W) ? 1.0f : 0.0f;
            float vy1 = (y0+1 >= 0 && y0+1 < IMG_W) ? 1.0f : 0.0f;
            float w00 = (1.0f-wx)*(1.0f-wy)*vx0*vy0;
            float w10 = wx*(1.0f-wy)*vx1*vy0;
            float w01 = (1.0f-wx)*wy*vx0*vy1;
            float w11 = wx*wy*vx1*vy1;
            int xi0 = min(max(x0,   0), IMG_H-1), xi1 = min(max(x0+1, 0), IMG_H-1);
            int yi0 = min(max(y0,   0), IMG_W-1), yi1 = min(max(y0+1, 0), IMG_W-1);
            const float2* pv = (const float2*)(vd_t) + (size_t)b * (IMG_H*IMG_W);
            float2 t00 = pv[xi0*IMG_W + yi0], t01 = pv[xi0*IMG_W + yi1];
            float2 t10 = pv[xi1*IMG_W + yi0], t11 = pv[xi1*IMG_W + yi1];
            vsum  += w00*t00.x + w01*t01.x + w10*t10.x + w11*t11.x;
            ndsum += w00*t00.y + w01*t01.y + w10*t10.y + w11*t11.y;
        }
    }

    float invd = 1.0f / (wsum + 1e-6f);
    // channel stores: per instruction, even lanes write channel k (128B contiguous),
    // odd lanes write channel 16+k (128B contiguous) -> full lines, no amplification
    #pragma unroll
    for (int q = 0; q < 4; q++) {
        #pragma unroll
        for (int k = 0; k < 4; k++) {
            float fv = (&facc[q].x)[k] * invd;
            __builtin_nontemporal_store(fv, &out[(size_t)(16*j + 4*q + k) * NVOX + n]);
        }
    }
    if (j == 0) {
        __builtin_nontemporal_store(vsum  * invd, &out[(size_t)CCH*NVOX + n]);
        __builtin_nontemporal_store(zsum  * invd, &out[(size_t)CCH*NVOX + NVOX + n]);
        __builtin_nontemporal_store(ndsum * invd, &out[(size_t)CCH*NVOX + 2*(size_t)NVOX + n]);
    }
}

// ---------------- fallback (original layouts, one thread per voxel) --------------
__global__ __launch_bounds__(256) void mvmap_main(
    const float* __restrict__ img_feats,
    const float* __restrict__ variances,
    const float* __restrict__ render_depth,
    const float* __restrict__ coords,
    const float* __restrict__ Ps,
    const float* __restrict__ Ks,
    float* __restrict__ out)
{
    __shared__ float sW2C[NCAMS][12];
    __shared__ float sK[NCAMS][9];

    if (threadIdx.x < NCAMS) {
        int b = threadIdx.x;
        const float* P = Ps + b * 16;
        float r00=P[0], r01=P[1], r02=P[2],  tx=P[3];
        float r10=P[4], r11=P[5], r12=P[6],  ty=P[7];
        float r20=P[8], r21=P[9], r22=P[10], tz=P[11];
        float det = r00*(r11*r22 - r12*r21)
                  - r01*(r10*r22 - r12*r20)
                  + r02*(r10*r21 - r11*r20);
        float id = 1.0f / det;
        float i00 =  (r11*r22 - r12*r21) * id;
        float i01 = -(r01*r22 - r02*r21) * id;
        float i02 =  (r01*r12 - r02*r11) * id;
        float i10 = -(r10*r22 - r12*r20) * id;
        float i11 =  (r00*r22 - r02*r20) * id;
        float i12 = -(r00*r12 - r02*r10) * id;
        float i20 =  (r10*r21 - r11*r20) * id;
        float i21 = -(r00*r21 - r01*r20) * id;
        float i22 =  (r00*r11 - r01*r10) * id;
        sW2C[b][0]=i00; sW2C[b][1]=i01; sW2C[b][2] =i02; sW2C[b][3] =-(i00*tx + i01*ty + i02*tz);
        sW2C[b][4]=i10; sW2C[b][5]=i11; sW2C[b][6] =i12; sW2C[b][7] =-(i10*tx + i11*ty + i12*tz);
        sW2C[b][8]=i20; sW2C[b][9]=i21; sW2C[b][10]=i22; sW2C[b][11]=-(i20*tx + i21*ty + i22*tz);
        #pragma unroll
        for (int jj = 0; jj < 9; jj++) sK[b][jj] = Ks[b*9 + jj];
    }
    __syncthreads();

    int n = blockIdx.x * blockDim.x + threadIdx.x;
    if (n >= NVOX) return;

    float px = coords[3*n + 0];
    float pz = coords[3*n + 1];
    float ph = coords[3*n + 2];

    float fsum[CCH];
    #pragma unroll
    for (int c = 0; c < CCH; c++) fsum[c] = 0.0f;
    float wsum = 0.0f, vsum = 0.0f, ndsum = 0.0f, zsum = 0.0f;

    for (int b = 0; b < NCAMS; b++) {
        float cx = sW2C[b][0]*px + sW2C[b][1]*pz + sW2C[b][2] *ph + sW2C[b][3];
        float cy = sW2C[b][4]*px + sW2C[b][5]*pz + sW2C[b][6] *ph + sW2C[b][7];
        float cz = sW2C[b][8]*px + sW2C[b][9]*pz + sW2C[b][10]*ph + sW2C[b][11];
        float u0 = sK[b][0]*cx + sK[b][1]*cy + sK[b][2]*cz;
        float v0 = sK[b][3]*cx + sK[b][4]*cy + sK[b][5]*cz;
        float zc = sK[b][6]*cx + sK[b][7]*cy + sK[b][8]*cz;
        float zsafe = (fabsf(zc) < 1e-6f) ? 1e-6f : zc;
        float u = u0 / zsafe;
        float v = v0 / zsafe;
        bool mask = (zc > 1e-3f) && (u >= 0.0f) && (u < (float)IMG_W)
                                 && (v >= 0.0f) && (v < (float)IMG_H);
        if (!mask) continue;

        wsum += 1.0f;
        zsum += zc;
        {
            float xf = v * 0.25f - 0.5f;
            float yf = u * 0.25f - 0.5f;
            float x0f = floorf(xf), y0f = floorf(yf);
            float wx = xf - x0f, wy = yf - y0f;
            int x0 = (int)x0f, y0 = (int)y0f;
            float vx0 = (x0   >= 0 && x0   < FXV) ? 1.0f : 0.0f;
            float vx1 = (x0+1 >= 0 && x0+1 < FXV) ? 1.0f : 0.0f;
            float vy0 = (y0   >= 0 && y0   < FZV) ? 1.0f : 0.0f;
            float vy1 = (y0+1 >= 0 && y0+1 < FZV) ? 1.0f : 0.0f;
            float w00 = (1.0f-wx)*(1.0f-wy)*vx0*vy0;
            float w10 = wx*(1.0f-wy)*vx1*vy0;
            float w01 = (1.0f-wx)*wy*vx0*vy1;
            float w11 = wx*wy*vx1*vy1;
            int xi0 = min(max(x0,   0), FXV-1), xi1 = min(max(x0+1, 0), FXV-1);
            int yi0 = min(max(y0,   0), FZV-1), yi1 = min(max(y0+1, 0), FZV-1);
            int o00 = xi0*FZV + yi0, o01 = xi0*FZV + yi1;
            int o10 = xi1*FZV + yi0, o11 = xi1*FZV + yi1;
            const float* p = img_feats + (size_t)b * (CCH*FXV*FZV);
            #pragma unroll
            for (int c = 0; c < CCH; c++) {
                const float* pc = p + c * (FXV*FZV);
                fsum[c] += w00*pc[o00] + w01*pc[o01] + w10*pc[o10] + w11*pc[o11];
            }
        }
        {
            float xf = v - 0.5f;
            float yf = u - 0.5f;
            float x0f = floorf(xf), y0f = floorf(yf);
            float wx = xf - x0f, wy = yf - y0f;
            int x0 = (int)x0f, y0 = (int)y0f;
            float vx0 = (x0   >= 0 && x0   < IMG_H) ? 1.0f : 0.0f;
            float vx1 = (x0+1 >= 0 && x0+1 < IMG_H) ? 1.0f : 0.0f;
            float vy0 = (y0   >= 0 && y0   < IMG_W) ? 1.0f : 0.0f;
            float vy1 = (y0+1 >= 0 && y0+1 < IMG_W) ? 1.0f : 0.0f;
            float w00 = (1.0f-wx)*(1.0f-wy)*vx0*vy0;
            float w10 = wx*(1.0f-wy)*vx1*vy0;
            float w01 = (1.0f-wx)*wy*vx0*vy1;
            float w11 = wx*wy*vx1*vy1;
            int xi0 = min(max(x0,   0), IMG_H-1), xi1 = min(max(x0+1, 0), IMG_H-1);
            int yi0 = min(max(y0,   0), IMG_W-1), yi1 = min(max(y0+1, 0), IMG_W-1);
            int o00 = xi0*IMG_W + yi0, o01 = xi0*IMG_W + yi1;
            int o10 = xi1*IMG_W + yi0, o11 = xi1*IMG_W + yi1;
            const float* pv = variances    + (size_t)b * (IMG_H*IMG_W);
            const float* pd = render_depth + (size_t)b * (IMG_H*IMG_W);
            vsum  += w00*pv[o00] + w01*pv[o01] + w10*pv[o10] + w11*pv[o11];
            ndsum += w00*pd[o00] + w01*pd[o01] + w10*pd[o10] + w11*pd[o11];
        }
    }

    float invd = 1.0f / (wsum + 1e-6f);
    #pragma unroll
    for (int c = 0; c < CCH; c++) out[(size_t)c * NVOX + n] = fsum[c] * invd;
    out[(size_t)CCH*NVOX + n]              = vsum  * invd;
    out[(size_t)CCH*NVOX + NVOX + n]       = vsum == vsum ? zsum * invd : zsum * invd;
    out[(size_t)CCH*NVOX + NVOX + n]       = zsum  * invd;
    out[(size_t)CCH*NVOX + 2*(size_t)NVOX + n] = ndsum * invd;
}

extern "C" void kernel_launch(void* const* d_in, const int* in_sizes, int n_in,
                              void* d_out, int out_size, void* d_ws, size_t ws_size,
                              hipStream_t stream) {
    const float* img_feats    = (const float*)d_in[0];
    const float* variances    = (const float*)d_in[1];
    const float* render_depth = (const float*)d_in[2];
    const float* coords       = (const float*)d_in[3];
    const float* Ps           = (const float*)d_in[4];
    const float* Ks           = (const float*)d_in[5];
    float* out = (float*)d_out;

    if (ws_size >= WS_NEED_BYTES) {
        float* feats_t = (float*)d_ws;
        float* vd_t    = feats_t + FEATS_T_ELEMS;
        {
            int total = NF + NV;
            hipLaunchKernelGGL(prep_all, dim3((total + 255) / 256), dim3(256), 0, stream,
                               img_feats, variances, render_depth, feats_t, vd_t);
        }
        hipLaunchKernelGGL(mvmap_fast, dim3((2 * NVOX) / 128), dim3(128), 0, stream,
                           feats_t, vd_t, coords, Ps, Ks, out);
    } else {
        hipLaunchKernelGGL(mvmap_main, dim3(NVOX / 256), dim3(256), 0, stream,
                           img_feats, variances, render_depth, coords, Ps, Ks, out);
    }
}